// Round 2
// baseline (9.620 us; speedup 1.0000x reference)
//
#include <hip/hip_runtime.h>

// QNN collapses analytically: RZ phases cancel in |amp|^2 (weights input is
// provably unused), CNOT ring is a GF(2)-linear basis permutation, and the
// product state factorizes each expectation into a product of per-qubit
// cos(enc_offset[m] + enc_scale[m]*x[m]).
// Masks (verified by 24-step mask simulation of the CNOT ring x3):
//   S0={1,4,5} S1={1,2,4,6} S2={2,3,5,7} S3={0,3,4,6} S4={0,1,4,5,7}
//   S5={1,2,5,6} S6={2,3,6,7} S7={0,3,4,7}  S_parity={0,4}
//
// 2 samples/thread: 64 B contiguous read (4x dwordx4), 16 B float4 store.
// 128-thread blocks keep the grid at 256 workgroups -> all 256 CUs covered.

__device__ __forceinline__ void qnn_sample(const float xs[8],
                                           const float off[8], const float sc[8],
                                           const float* __restrict__ W,
                                           float b0, float b1,
                                           float& o0, float& o1)
{
    float c[8];
#pragma unroll
    for (int m = 0; m < 8; ++m)
        c[m] = __cosf(fmaf(sc[m], xs[m], off[m]));

    float c14 = c[1] * c[4];
    float c23 = c[2] * c[3];
    float c04 = c[0] * c[4];

    float f[9];
    f[0] = c14 * c[5];
    f[1] = c14 * c[2] * c[6];
    f[2] = c23 * c[5] * c[7];
    f[3] = c04 * c[3] * c[6];
    f[4] = c04 * c[1] * c[5] * c[7];
    f[5] = c[1] * c[2] * c[5] * c[6];
    f[6] = c23 * c[6] * c[7];
    f[7] = c04 * c[3] * c[7];
    f[8] = c04;

    o0 = b0;
    o1 = b1;
#pragma unroll
    for (int k = 0; k < 9; ++k) {
        o0 = fmaf(f[k], W[k], o0);
        o1 = fmaf(f[k], W[9 + k], o1);
    }
}

__global__ __launch_bounds__(128) void qnn_kernel(
    const float* __restrict__ x,    // (B, 8)
    const float* __restrict__ off,  // (8,)
    const float* __restrict__ sc,   // (8,)
    const float* __restrict__ W,    // (2, 9) row-major
    const float* __restrict__ bias, // (2,)
    float* __restrict__ out,        // (B, 2)
    int Bpairs)                     // B/2
{
    int i = blockIdx.x * blockDim.x + threadIdx.x;
    if (i >= Bpairs) return;

    // uniform scalars (compiler emits s_load)
    float offl[8], scl[8];
#pragma unroll
    for (int m = 0; m < 8; ++m) { offl[m] = off[m]; scl[m] = sc[m]; }
    float b0 = bias[0], b1 = bias[1];

    // 64 contiguous bytes per thread: samples 2i and 2i+1
    const float4* xv = reinterpret_cast<const float4*>(x + (size_t)i * 16);
    float4 v0 = xv[0], v1 = xv[1], v2 = xv[2], v3 = xv[3];

    float xsA[8] = {v0.x, v0.y, v0.z, v0.w, v1.x, v1.y, v1.z, v1.w};
    float xsB[8] = {v2.x, v2.y, v2.z, v2.w, v3.x, v3.y, v3.z, v3.w};

    float a0, a1, c0, c1;
    qnn_sample(xsA, offl, scl, W, b0, b1, a0, a1);
    qnn_sample(xsB, offl, scl, W, b0, b1, c0, c1);

    reinterpret_cast<float4*>(out)[i] = make_float4(a0, a1, c0, c1);
}

extern "C" void kernel_launch(void* const* d_in, const int* in_sizes, int n_in,
                              void* d_out, int out_size, void* d_ws, size_t ws_size,
                              hipStream_t stream)
{
    // setup_inputs order: x, weights (unused), enc_offset, enc_scale, W, b
    const float* x    = (const float*)d_in[0];
    const float* off  = (const float*)d_in[2];
    const float* sc   = (const float*)d_in[3];
    const float* W    = (const float*)d_in[4];
    const float* bias = (const float*)d_in[5];
    float* out = (float*)d_out;

    int B = in_sizes[0] / 8;
    int Bpairs = B / 2;                 // B = 65536, even
    int threads = 128;
    int blocks = (Bpairs + threads - 1) / threads;  // 256 blocks
    qnn_kernel<<<blocks, threads, 0, stream>>>(x, off, sc, W, bias, out, Bpairs);
}